// Round 1
// baseline (704.774 us; speedup 1.0000x reference)
//
#include <hip/hip_runtime.h>

#define NB 4
#define NH 12
#define NS 2048
#define PD 64
#define BN 64
#define BM 64
#define LDP 68   // padded LDS stride (floats); 68%4==0 keeps float4 alignment

static __device__ __forceinline__ float dot4(const float4& a, const float4& b) {
    return fmaf(a.x, b.x, fmaf(a.y, b.y, fmaf(a.z, b.z, a.w * b.w)));
}

__global__ __launch_bounds__(256) void kde_attn_kernel(
    const float* __restrict__ Qg, const float* __restrict__ Kg,
    const float* __restrict__ Vg, const float* __restrict__ maskg,
    float* __restrict__ Xg)
{
    __shared__ float sQ [BN][LDP];
    __shared__ float sKP[BM][LDP];   // K during S-phase, then attn P tile
    __shared__ float sV [BM][LDP];
    __shared__ float sdQ[BN];
    __shared__ float scb[BM];        // -diagK - 1e9*(1-mask)
    __shared__ float red[4];

    const int t  = threadIdx.x;
    const int tx = t & 15;
    const int ty = t >> 4;
    const int bh = blockIdx.y;
    const int b  = bh / NH;
    const int n0 = blockIdx.x * BN;

    const float DN = 0.42044820762685725f;   // 32^(-0.25)

    const float* Qh = Qg + (size_t)bh * NS * PD;
    const float* Kh = Kg + (size_t)bh * NS * PD;
    const float* Vh = Vg + (size_t)bh * NS * PD;
    const float* mk = maskg + (size_t)b * NS;

    // ---- non_padding_num = sum(mask[b,:]) (exact for 0/1 masks) ----
    {
        float s = 0.f;
        for (int i = t; i < NS; i += 256) s += mk[i];
        #pragma unroll
        for (int m = 1; m < 64; m <<= 1) s += __shfl_xor(s, m);
        if ((t & 63) == 0) red[t >> 6] = s;
    }
    __syncthreads();
    const float npn = red[0] + red[1] + red[2] + red[3];
    const float vsc = DN / npn;

    // ---- load Q tile (scaled by mask*DN), compute diag_Q ----
    {
        const int r  = t >> 4;
        const int c4 = (t & 15) * 4;
        float sq[4];
        #pragma unroll
        for (int i = 0; i < 4; ++i) {
            const int row = r + 16 * i;
            const float qs = mk[n0 + row] * DN;
            float4 v = *(const float4*)(Qh + (size_t)(n0 + row) * PD + c4);
            v.x *= qs; v.y *= qs; v.z *= qs; v.w *= qs;
            *(float4*)&sQ[row][c4] = v;
            sq[i] = dot4(v, v);
        }
        #pragma unroll
        for (int m = 1; m < 16; m <<= 1) {
            #pragma unroll
            for (int i = 0; i < 4; ++i) sq[i] += __shfl_xor(sq[i], m);
        }
        if (tx == 0) {
            #pragma unroll
            for (int i = 0; i < 4; ++i) sdQ[r + 16 * i] = 0.5f * sq[i];
        }
    }

    float Xa[4][4];
    #pragma unroll
    for (int i = 0; i < 4; ++i)
        #pragma unroll
        for (int j = 0; j < 4; ++j) Xa[i][j] = 0.f;

    for (int mt = 0; mt < NS / BM; ++mt) {
        const int m0 = mt * BM;

        // ---- load K,V tiles (scaled), compute column bias ----
        {
            const int r  = t >> 4;
            const int c4 = (t & 15) * 4;
            float sq[4], mv[4];
            #pragma unroll
            for (int i = 0; i < 4; ++i) {
                const int row = r + 16 * i;
                const float m  = mk[m0 + row];
                mv[i] = m;
                const float ks = m * DN;
                const float vs = m * vsc;
                float4 kv = *(const float4*)(Kh + (size_t)(m0 + row) * PD + c4);
                float4 vv = *(const float4*)(Vh + (size_t)(m0 + row) * PD + c4);
                kv.x *= ks; kv.y *= ks; kv.z *= ks; kv.w *= ks;
                vv.x *= vs; vv.y *= vs; vv.z *= vs; vv.w *= vs;
                *(float4*)&sKP[row][c4] = kv;
                *(float4*)&sV [row][c4] = vv;
                sq[i] = dot4(kv, kv);
            }
            #pragma unroll
            for (int m = 1; m < 16; m <<= 1) {
                #pragma unroll
                for (int i = 0; i < 4; ++i) sq[i] += __shfl_xor(sq[i], m);
            }
            if (tx == 0) {
                #pragma unroll
                for (int i = 0; i < 4; ++i)
                    scb[r + 16 * i] = fmaf(-1.0e9f, 1.f - mv[i], -0.5f * sq[i]);
            }
        }
        __syncthreads();   // tiles + scb ready

        // ---- S = Qs . Ks^T  (rows 4ty+i, cols tx+16j) ----
        float S[4][4];
        #pragma unroll
        for (int i = 0; i < 4; ++i)
            #pragma unroll
            for (int j = 0; j < 4; ++j) S[i][j] = 0.f;

        #pragma unroll
        for (int k4 = 0; k4 < 16; ++k4) {
            float4 qv4[4], kv4[4];
            #pragma unroll
            for (int i = 0; i < 4; ++i) qv4[i] = *(const float4*)&sQ [4 * ty + i ][4 * k4];
            #pragma unroll
            for (int j = 0; j < 4; ++j) kv4[j] = *(const float4*)&sKP[tx + 16 * j][4 * k4];
            #pragma unroll
            for (int i = 0; i < 4; ++i) {
                #pragma unroll
                for (int j = 0; j < 4; ++j) {
                    float a = S[i][j];
                    a = fmaf(qv4[i].x, kv4[j].x, a);
                    a = fmaf(qv4[i].y, kv4[j].y, a);
                    a = fmaf(qv4[i].z, kv4[j].z, a);
                    a = fmaf(qv4[i].w, kv4[j].w, a);
                    S[i][j] = a;
                }
            }
        }
        __syncthreads();   // done reading sKP as K

        // ---- attn = exp(S - diagQ + cb) -> sKP becomes P ----
        #pragma unroll
        for (int i = 0; i < 4; ++i) {
            const float dq = sdQ[4 * ty + i];
            #pragma unroll
            for (int j = 0; j < 4; ++j) {
                sKP[4 * ty + i][tx + 16 * j] = __expf(S[i][j] - dq + scb[tx + 16 * j]);
            }
        }
        __syncthreads();   // P ready

        // ---- X += P . Vs  (rows 4ty+i, cols 4tx+j) ----
        #pragma unroll
        for (int m4 = 0; m4 < 16; ++m4) {
            float4 pv4[4], vv4[4];
            #pragma unroll
            for (int i = 0; i < 4; ++i) pv4[i] = *(const float4*)&sKP[4 * ty + i][4 * m4];
            #pragma unroll
            for (int e = 0; e < 4; ++e) vv4[e] = *(const float4*)&sV[4 * m4 + e][4 * tx];
            const float* vp0 = (const float*)&vv4[0];
            const float* vp1 = (const float*)&vv4[1];
            const float* vp2 = (const float*)&vv4[2];
            const float* vp3 = (const float*)&vv4[3];
            #pragma unroll
            for (int i = 0; i < 4; ++i) {
                const float px = pv4[i].x, py = pv4[i].y, pz = pv4[i].z, pw = pv4[i].w;
                #pragma unroll
                for (int j = 0; j < 4; ++j) {
                    float a = Xa[i][j];
                    a = fmaf(px, vp0[j], a);
                    a = fmaf(py, vp1[j], a);
                    a = fmaf(pz, vp2[j], a);
                    a = fmaf(pw, vp3[j], a);
                    Xa[i][j] = a;
                }
            }
        }
        __syncthreads();   // done reading sKP/sV
    }

    // ---- write out ----
    float* Xh = Xg + (size_t)bh * NS * PD;
    #pragma unroll
    for (int i = 0; i < 4; ++i) {
        float4 o = make_float4(Xa[i][0], Xa[i][1], Xa[i][2], Xa[i][3]);
        *(float4*)(Xh + (size_t)(n0 + 4 * ty + i) * PD + 4 * tx) = o;
    }
}

extern "C" void kernel_launch(void* const* d_in, const int* in_sizes, int n_in,
                              void* d_out, int out_size, void* d_ws, size_t ws_size,
                              hipStream_t stream) {
    const float* Q    = (const float*)d_in[0];
    const float* K    = (const float*)d_in[1];
    const float* V    = (const float*)d_in[2];
    const float* mask = (const float*)d_in[3];
    float* X = (float*)d_out;

    dim3 grid(NS / BN, NB * NH);
    kde_attn_kernel<<<grid, dim3(256), 0, stream>>>(Q, K, V, mask, X);
}

// Round 2
// 395.776 us; speedup vs baseline: 1.7807x; 1.7807x over previous
//
#include <hip/hip_runtime.h>
#include <hip/hip_bf16.h>

#define NB 4
#define NH 12
#define NS 2048
#define PD 64
#define LDA 72   // ushort stride (144 B) for sQ/sK/sVt: 16B-aligned rows, spreads banks
#define LDP 68   // uint stride (272 B) for sP

typedef float f32x4 __attribute__((ext_vector_type(4)));
typedef short s16x8 __attribute__((ext_vector_type(8)));

#define MFMA(a, b, c) __builtin_amdgcn_mfma_f32_16x16x32_bf16((a), (b), (c), 0, 0, 0)

static __device__ __forceinline__ unsigned short bfbits(float x) {
    __hip_bfloat16 h = __float2bfloat16(x);            // RNE
    union { __hip_bfloat16 b; unsigned short u; } c; c.b = h; return c.u;
}
static __device__ __forceinline__ float bf2f(unsigned short u) {
    union { unsigned int i; float f; } c; c.i = ((unsigned int)u) << 16; return c.f;
}
static __device__ __forceinline__ float dot4(const float4& a) {
    return fmaf(a.x, a.x, fmaf(a.y, a.y, fmaf(a.z, a.z, a.w * a.w)));
}
// split float4 into bf16 hi (h4) and lo (l4), each packed as ushort4-in-uint2
static __device__ __forceinline__ void split4(float4 v, uint2& h4, uint2& l4) {
    unsigned short h0 = bfbits(v.x), h1 = bfbits(v.y), h2 = bfbits(v.z), h3 = bfbits(v.w);
    unsigned short l0 = bfbits(v.x - bf2f(h0)), l1 = bfbits(v.y - bf2f(h1));
    unsigned short l2 = bfbits(v.z - bf2f(h2)), l3 = bfbits(v.w - bf2f(h3));
    h4.x = (unsigned)h0 | ((unsigned)h1 << 16); h4.y = (unsigned)h2 | ((unsigned)h3 << 16);
    l4.x = (unsigned)l0 | ((unsigned)l1 << 16); l4.y = (unsigned)l2 | ((unsigned)l3 << 16);
}
// 8 packed u32 (hi in low16, lo in high16) -> two s16x8 frags
static __device__ __forceinline__ void unpack8(uint4 a, uint4 b, s16x8& hf, s16x8& lf) {
    union { uint4 u; s16x8 v; } ch, cl;
#if __has_builtin(__builtin_amdgcn_perm)
    ch.u.x = __builtin_amdgcn_perm(a.y, a.x, 0x05040100u);
    ch.u.y = __builtin_amdgcn_perm(a.w, a.z, 0x05040100u);
    ch.u.z = __builtin_amdgcn_perm(b.y, b.x, 0x05040100u);
    ch.u.w = __builtin_amdgcn_perm(b.w, b.z, 0x05040100u);
    cl.u.x = __builtin_amdgcn_perm(a.y, a.x, 0x07060302u);
    cl.u.y = __builtin_amdgcn_perm(a.w, a.z, 0x07060302u);
    cl.u.z = __builtin_amdgcn_perm(b.y, b.x, 0x07060302u);
    cl.u.w = __builtin_amdgcn_perm(b.w, b.z, 0x07060302u);
#else
    ch.u.x = (a.x & 0xffffu) | (a.y << 16); ch.u.y = (a.z & 0xffffu) | (a.w << 16);
    ch.u.z = (b.x & 0xffffu) | (b.y << 16); ch.u.w = (b.z & 0xffffu) | (b.w << 16);
    cl.u.x = (a.x >> 16) | (a.y & 0xffff0000u); cl.u.y = (a.z >> 16) | (a.w & 0xffff0000u);
    cl.u.z = (b.x >> 16) | (b.y & 0xffff0000u); cl.u.w = (b.z >> 16) | (b.w & 0xffff0000u);
#endif
    hf = ch.v; lf = cl.v;
}

__global__ __launch_bounds__(256, 2) void kde_attn_mfma(
    const float* __restrict__ Qg, const float* __restrict__ Kg,
    const float* __restrict__ Vg, const float* __restrict__ maskg,
    float* __restrict__ Xg)
{
    __shared__ __align__(16) unsigned short sQh[64 * LDA], sQl[64 * LDA];
    __shared__ __align__(16) unsigned short sKh[64 * LDA], sKl[64 * LDA];
    __shared__ __align__(16) unsigned short sVth[64 * LDA], sVtl[64 * LDA]; // [p][m]
    __shared__ __align__(16) unsigned int   sP[64 * LDP];                  // hi|lo<<16
    __shared__ float sdQ[64], scb[64], red[4];

    const int t    = threadIdx.x;
    const int lane = t & 63;
    const int w    = t >> 6;
    const int wr   = w >> 1;
    const int wc   = w & 1;
    const int lq   = lane & 15;
    const int lk   = lane >> 4;

    // XCD-bijective remap: 1536 blocks = 8 XCD * (6 bh * 32 qb)
    const int s   = blockIdx.x;
    const int xcd = s & 7;
    const int ii  = s >> 3;
    const int bh  = 6 * xcd + (ii >> 5);
    const int n0  = (ii & 31) * 64;
    const int b   = bh / NH;

    const float DN = 0.42044820762685725f;  // 32^(-0.25)

    const float* Qh = Qg + (size_t)bh * NS * PD;
    const float* Kh = Kg + (size_t)bh * NS * PD;
    const float* Vh = Vg + (size_t)bh * NS * PD;
    const float* mk = maskg + (size_t)b * NS;

    // ---- npn (sum of mask) ----
    {
        float sm = 0.f;
        for (int i = t; i < NS; i += 256) sm += mk[i];
        #pragma unroll
        for (int m = 1; m < 64; m <<= 1) sm += __shfl_xor(sm, m);
        if (lane == 0) red[w] = sm;
    }

    // ---- stage Q (scaled, split) + diag_Q ----
    #pragma unroll
    for (int j = 0; j < 4; ++j) {
        const int idx = j * 256 + t;
        const int row = idx >> 4;
        const int u   = idx & 15;
        const float qs = mk[n0 + row] * DN;
        float4 v = *(const float4*)(Qh + (size_t)(n0 + row) * PD + 4 * u);
        v.x *= qs; v.y *= qs; v.z *= qs; v.w *= qs;
        uint2 h4, l4; split4(v, h4, l4);
        *(uint2*)&sQh[row * LDA + 4 * u] = h4;
        *(uint2*)&sQl[row * LDA + 4 * u] = l4;
        float d = dot4(v);
        d += __shfl_xor(d, 1); d += __shfl_xor(d, 2);
        d += __shfl_xor(d, 4); d += __shfl_xor(d, 8);
        if (u == 0) sdQ[row] = 0.5f * d;
    }
    __syncthreads();

    const float npn = red[0] + red[1] + red[2] + red[3];
    const float vscl = DN / npn;

    float dqv[2][4];
    #pragma unroll
    for (int i2 = 0; i2 < 2; ++i2)
        #pragma unroll
        for (int r = 0; r < 4; ++r)
            dqv[i2][r] = sdQ[32 * wr + 16 * i2 + 4 * lk + r];

    f32x4 xacc[2][2];
    #pragma unroll
    for (int i2 = 0; i2 < 2; ++i2)
        #pragma unroll
        for (int j2 = 0; j2 < 2; ++j2)
            xacc[i2][j2] = (f32x4){0.f, 0.f, 0.f, 0.f};

    for (int mt = 0; mt < NS / 64; ++mt) {
        const int m0 = mt * 64;

        // ---- stage K (scaled, split) + column bias ----
        #pragma unroll
        for (int j = 0; j < 4; ++j) {
            const int idx = j * 256 + t;
            const int row = idx >> 4;
            const int u   = idx & 15;
            const float mr = mk[m0 + row];
            const float ks = mr * DN;
            float4 v = *(const float4*)(Kh + (size_t)(m0 + row) * PD + 4 * u);
            v.x *= ks; v.y *= ks; v.z *= ks; v.w *= ks;
            uint2 h4, l4; split4(v, h4, l4);
            *(uint2*)&sKh[row * LDA + 4 * u] = h4;
            *(uint2*)&sKl[row * LDA + 4 * u] = l4;
            float d = dot4(v);
            d += __shfl_xor(d, 1); d += __shfl_xor(d, 2);
            d += __shfl_xor(d, 4); d += __shfl_xor(d, 8);
            if (u == 0) scb[row] = fmaf(-1.0e9f, 1.f - mr, -0.5f * d);
        }
        // ---- stage V transposed (scaled, split): sVt[p][m] ----
        #pragma unroll
        for (int j = 0; j < 4; ++j) {
            const int idx = j * 256 + t;
            const int p   = idx & 63;
            const int mq  = idx >> 6;           // constant per wave-instruction
            const float* vc = Vh + (size_t)(m0 + 4 * mq) * PD + p;
            float4 mr = *(const float4*)&mk[m0 + 4 * mq];
            float4 v = make_float4(vc[0] * (mr.x * vscl), vc[PD] * (mr.y * vscl),
                                   vc[2 * PD] * (mr.z * vscl), vc[3 * PD] * (mr.w * vscl));
            uint2 h4, l4; split4(v, h4, l4);
            *(uint2*)&sVth[p * LDA + 4 * mq] = h4;
            *(uint2*)&sVtl[p * LDA + 4 * mq] = l4;
        }
        __syncthreads();

        float cbv[2];
        #pragma unroll
        for (int j2 = 0; j2 < 2; ++j2) cbv[j2] = scb[32 * wc + 16 * j2 + lq];

        // ---- S = Qs.Ks^T via split MFMA ----
        f32x4 acc[2][2];
        #pragma unroll
        for (int i2 = 0; i2 < 2; ++i2)
            #pragma unroll
            for (int j2 = 0; j2 < 2; ++j2)
                acc[i2][j2] = (f32x4){0.f, 0.f, 0.f, 0.f};

        #pragma unroll
        for (int ks = 0; ks < 2; ++ks) {
            s16x8 ah[2], al[2], kh[2], kl[2];
            #pragma unroll
            for (int i2 = 0; i2 < 2; ++i2) {
                const int ro = (32 * wr + 16 * i2 + lq) * LDA + 32 * ks + 8 * lk;
                ah[i2] = *(const s16x8*)&sQh[ro];
                al[i2] = *(const s16x8*)&sQl[ro];
            }
            #pragma unroll
            for (int j2 = 0; j2 < 2; ++j2) {
                const int ro = (32 * wc + 16 * j2 + lq) * LDA + 32 * ks + 8 * lk;
                kh[j2] = *(const s16x8*)&sKh[ro];
                kl[j2] = *(const s16x8*)&sKl[ro];
            }
            #pragma unroll
            for (int i2 = 0; i2 < 2; ++i2)
                #pragma unroll
                for (int j2 = 0; j2 < 2; ++j2) {
                    acc[i2][j2] = MFMA(ah[i2], kh[j2], acc[i2][j2]);
                    acc[i2][j2] = MFMA(ah[i2], kl[j2], acc[i2][j2]);
                    acc[i2][j2] = MFMA(al[i2], kh[j2], acc[i2][j2]);
                }
        }

        // ---- P = exp(S - diagQ + cb), split to bf16 hi/lo, pack to LDS ----
        #pragma unroll
        for (int i2 = 0; i2 < 2; ++i2)
            #pragma unroll
            for (int j2 = 0; j2 < 2; ++j2) {
                #pragma unroll
                for (int r = 0; r < 4; ++r) {
                    const float P = __expf(acc[i2][j2][r] - dqv[i2][r] + cbv[j2]);
                    const unsigned short hb = bfbits(P);
                    const unsigned short lb = bfbits(P - bf2f(hb));
                    sP[(32 * wr + 16 * i2 + 4 * lk + r) * LDP + 32 * wc + 16 * j2 + lq] =
                        (unsigned)hb | ((unsigned)lb << 16);
                }
            }
        __syncthreads();

        // ---- X += P . Vs via split MFMA ----
        #pragma unroll
        for (int ks2 = 0; ks2 < 2; ++ks2) {
            s16x8 ph[2], pl[2], vh[2], vl[2];
            #pragma unroll
            for (int i2 = 0; i2 < 2; ++i2) {
                const uint4* pp = (const uint4*)&sP[(32 * wr + 16 * i2 + lq) * LDP + 32 * ks2 + 8 * lk];
                unpack8(pp[0], pp[1], ph[i2], pl[i2]);
            }
            #pragma unroll
            for (int j2 = 0; j2 < 2; ++j2) {
                const int ro = (32 * wc + 16 * j2 + lq) * LDA + 32 * ks2 + 8 * lk;
                vh[j2] = *(const s16x8*)&sVth[ro];
                vl[j2] = *(const s16x8*)&sVtl[ro];
            }
            #pragma unroll
            for (int i2 = 0; i2 < 2; ++i2)
                #pragma unroll
                for (int j2 = 0; j2 < 2; ++j2) {
                    xacc[i2][j2] = MFMA(ph[i2], vh[j2], xacc[i2][j2]);
                    xacc[i2][j2] = MFMA(ph[i2], vl[j2], xacc[i2][j2]);
                    xacc[i2][j2] = MFMA(pl[i2], vh[j2], xacc[i2][j2]);
                }
        }
        __syncthreads();
    }

    // ---- write X ----
    float* Xh = Xg + (size_t)bh * NS * PD;
    #pragma unroll
    for (int i2 = 0; i2 < 2; ++i2)
        #pragma unroll
        for (int j2 = 0; j2 < 2; ++j2)
            #pragma unroll
            for (int r = 0; r < 4; ++r)
                Xh[(size_t)(n0 + 32 * wr + 16 * i2 + 4 * lk + r) * PD + 32 * wc + 16 * j2 + lq] =
                    xacc[i2][j2][r];
}

extern "C" void kernel_launch(void* const* d_in, const int* in_sizes, int n_in,
                              void* d_out, int out_size, void* d_ws, size_t ws_size,
                              hipStream_t stream) {
    const float* Q    = (const float*)d_in[0];
    const float* K    = (const float*)d_in[1];
    const float* V    = (const float*)d_in[2];
    const float* mask = (const float*)d_in[3];
    float* X = (float*)d_out;

    kde_attn_mfma<<<dim3(NB * NH * (NS / 64)), dim3(256), 0, stream>>>(Q, K, V, mask, X);
}